// Round 1
// baseline (410.864 us; speedup 1.0000x reference)
//
#include <hip/hip_runtime.h>
#include <hip/hip_bf16.h>

typedef __hip_bfloat16 bf16;
typedef __attribute__((ext_vector_type(8))) __bf16 bf16x8;
typedef __attribute__((ext_vector_type(4))) float f32x4;
typedef __attribute__((ext_vector_type(8))) unsigned short u16x8;

__device__ __forceinline__ void gld_lds16(const bf16* g, bf16* l) {
  __builtin_amdgcn_global_load_lds((const __attribute__((address_space(1))) void*)g,
                                   (__attribute__((address_space(3))) void*)l, 16, 0, 0);
}

// ---------------- weight prep: fp32 -> bf16, transposed layouts ----------------
__global__ __launch_bounds__(256) void prep_weights(
    const float* __restrict__ wq, const float* __restrict__ wk, const float* __restrict__ wv,
    const float* __restrict__ wo, const float* __restrict__ w1, const float* __restrict__ w2,
    bf16* __restrict__ WqkvT, bf16* __restrict__ woT, bf16* __restrict__ w1T, bf16* __restrict__ w2T)
{
  int i = blockIdx.x * 256 + threadIdx.x;
  if (i < 331776) {                 // WqkvT[n][d], n: 0..575 q, 576..1151 k, 1152..1727 v
    int n = i / 192, d = i % 192;
    int sel = n / 576, c = n % 576, h = c / 192, kd = c % 192;
    const float* w = (sel == 0) ? wq : (sel == 1 ? wk : wv);
    WqkvT[i] = __float2bfloat16(w[(d*3 + h)*192 + kd]);   // w[D][H][KD]
    return;
  }
  i -= 331776;
  if (i < 110592) {                 // woT[d][hk] = wo[hk][d], wo is [H*KD][D]
    int d = i / 576, hk = i % 576;
    woT[i] = __float2bfloat16(wo[hk*192 + d]);
    return;
  }
  i -= 110592;
  if (i < 147456) {                 // w1T[j][d] = w1[d][j], w1 is [192][768]
    int j = i / 192, d = i % 192;
    w1T[i] = __float2bfloat16(w1[d*768 + j]);
    return;
  }
  i -= 147456;
  if (i < 147456) {                 // w2T[d][j] = w2[j][d], w2 is [768][192]
    int d = i / 768, j = i % 768;
    w2T[i] = __float2bfloat16(w2[j*192 + d]);
  }
}

// ---------------- LayerNorm (D=192): 1 wave per row, 4 rows/block ----------------
__global__ __launch_bounds__(256) void ln_k(const float* __restrict__ x,
    const float* __restrict__ gamma, const float* __restrict__ beta,
    bf16* __restrict__ out)
{
  int row = blockIdx.x * 4 + (threadIdx.x >> 6);
  int lane = threadIdx.x & 63;
  const float* xr = x + (size_t)row * 192;
  float v0 = xr[lane], v1 = xr[lane + 64], v2 = xr[lane + 128];
  float s = v0 + v1 + v2;
  #pragma unroll
  for (int o = 32; o; o >>= 1) s += __shfl_xor(s, o);
  float mu = s * (1.f / 192.f);
  float d0 = v0 - mu, d1 = v1 - mu, d2 = v2 - mu;
  float q = d0*d0 + d1*d1 + d2*d2;
  #pragma unroll
  for (int o = 32; o; o >>= 1) q += __shfl_xor(q, o);
  float rs = rsqrtf(q * (1.f / 192.f) + 1e-3f);
  bf16* orow = out + (size_t)row * 192;
  orow[lane]       = __float2bfloat16(d0*rs*gamma[lane]       + beta[lane]);
  orow[lane + 64]  = __float2bfloat16(d1*rs*gamma[lane + 64]  + beta[lane + 64]);
  orow[lane + 128] = __float2bfloat16(d2*rs*gamma[lane + 128] + beta[lane + 128]);
}

// ---------------- generic GEMM C = A[M,K] * BT[N,K]^T, 128x64 tile, 4 waves ----------------
enum { EPI_QKV = 0, EPI_CTX = 1, EPI_RES = 2, EPI_GELU = 3, EPI_OUT = 4 };

template<int EPI>
__global__ __launch_bounds__(256) void gemm_bt(
    const bf16* __restrict__ Aall, const bf16* __restrict__ BTall,
    int M, int N, int K,
    float* __restrict__ outF, bf16* __restrict__ outB,
    const float* __restrict__ bias, const float* __restrict__ resF,
    bf16* __restrict__ q_out, bf16* __restrict__ k_out, bf16* __restrict__ vT_out,
    int b0)
{
  const int tid = threadIdx.x, lane = tid & 63, wid = tid >> 6;
  const int wm = wid >> 1, wn = wid & 1;
  const int row0 = blockIdx.y * 128, col0 = blockIdx.x * 64;
  const bf16* A = Aall;
  const bf16* BT = BTall;
  if (EPI == EPI_CTX) {   // batched over (b,g): z = zb*3+g within chunk
    A  = Aall + (size_t)blockIdx.z * 2048 * 2048;
    BT = BTall + ((size_t)b0 * 3 + blockIdx.z) * 192 * 2048;
  }
  __shared__ __align__(16) bf16 As[2][128 * 32];
  __shared__ __align__(16) bf16 Bs[2][64 * 32];
  f32x4 acc[4][2] = {};
  const int NT = K >> 5;

#define STAGE(buf_, kt_) do { \
    const bf16* Ab_ = A + (size_t)row0 * K + (kt_) * 32; \
    int c0_ = tid, r0_ = c0_ >> 2, cc0_ = (c0_ & 3) << 3; \
    gld_lds16(Ab_ + (size_t)r0_ * K + cc0_, &As[buf_][c0_ * 8]); \
    int c1_ = tid + 256, r1_ = c1_ >> 2, cc1_ = (c1_ & 3) << 3; \
    gld_lds16(Ab_ + (size_t)r1_ * K + cc1_, &As[buf_][c1_ * 8]); \
    const bf16* Bb_ = BT + (size_t)col0 * K + (kt_) * 32; \
    gld_lds16(Bb_ + (size_t)(tid >> 2) * K + ((tid & 3) << 3), &Bs[buf_][tid * 8]); \
  } while (0)

  STAGE(0, 0);
  for (int kt = 0; kt < NT; ++kt) {
    __syncthreads();
    const int buf = kt & 1;
    if (kt + 1 < NT) STAGE(buf ^ 1, kt + 1);
    const int koff = (lane >> 4) * 8;
    bf16x8 af[4], bfr[2];
    #pragma unroll
    for (int m = 0; m < 4; ++m)
      af[m] = *(const bf16x8*)&As[buf][(wm*64 + m*16 + (lane & 15))*32 + koff];
    #pragma unroll
    for (int n = 0; n < 2; ++n)
      bfr[n] = *(const bf16x8*)&Bs[buf][(wn*32 + n*16 + (lane & 15))*32 + koff];
    #pragma unroll
    for (int m = 0; m < 4; ++m)
      #pragma unroll
      for (int n = 0; n < 2; ++n)
        acc[m][n] = __builtin_amdgcn_mfma_f32_16x16x32_bf16(af[m], bfr[n], acc[m][n], 0, 0, 0);
  }
#undef STAGE

  const int rbase = row0 + wm * 64;
  const int cbase = col0 + wn * 32;
  #pragma unroll
  for (int m = 0; m < 4; ++m) {
    #pragma unroll
    for (int n = 0; n < 2; ++n) {
      const int col = cbase + n*16 + (lane & 15);
      const int rtop = rbase + m*16 + ((lane >> 4) << 2);
      #pragma unroll
      for (int j = 0; j < 4; ++j) {
        const int row = rtop + j;
        const float v = acc[m][n][j];
        if constexpr (EPI == EPI_QKV) {
          const int b = row >> 11, t = row & 2047;
          const int sel = col / 576, c2 = col % 576;
          const int h = c2 / 192, kd = c2 % 192;
          const bf16 bv = __float2bfloat16(v);
          const size_t hb_ = (size_t)(b * 3 + h);
          if (sel == 0)      q_out[(hb_ * 2048 + t) * 192 + kd] = bv;
          else if (sel == 1) k_out[(hb_ * 2048 + t) * 192 + kd] = bv;
          else               vT_out[(hb_ * 192 + kd) * 2048 + t] = bv;
        } else if constexpr (EPI == EPI_CTX) {
          const int b = b0 + (int)blockIdx.z / 3, g = (int)blockIdx.z % 3;
          outB[((size_t)b * 2048 + row) * 576 + g * 192 + col] = __float2bfloat16(v);
        } else if constexpr (EPI == EPI_RES) {
          const size_t idx = (size_t)row * 192 + col;
          outF[idx] = resF[idx] + v;
        } else if constexpr (EPI == EPI_GELU) {
          const float u = v + bias[col];
          outB[(size_t)row * 768 + col] =
              __float2bfloat16(0.5f * u * (1.f + erff(u * 0.70710678118654752f)));
        } else if constexpr (EPI == EPI_OUT) {
          const size_t idx = (size_t)row * 192 + col;
          outF[idx] = outF[idx] + v + bias[col];
        }
      }
    }
  }
}

// ---------------- scores: S_mix[g] = (sum_h pre_w[h,g] * Q_h K_h^T) / sqrt(192) ----------------
__global__ __launch_bounds__(256) void scores_k(
    const bf16* __restrict__ q, const bf16* __restrict__ k,
    const float* __restrict__ pre_w, bf16* __restrict__ S, int b0)
{
  const int tid = threadIdx.x, lane = tid & 63, wid = tid >> 6;
  const int wm = wid >> 1, wn = wid & 1;
  const int s0 = blockIdx.x * 64, t0 = blockIdx.y * 128;
  const int zb = blockIdx.z, b = b0 + zb;
  __shared__ __align__(16) bf16 Qs[2][128 * 32];
  __shared__ __align__(16) bf16 Ks[2][64 * 32];
  f32x4 acc[3][4][2] = {};

#define SSTAGE(buf_, h_, kt_) do { \
    const bf16* Qb_ = q + ((size_t)(b * 3 + (h_)) * 2048 + t0) * 192 + (kt_) * 32; \
    int c0_ = tid, r0_ = c0_ >> 2, cc0_ = (c0_ & 3) << 3; \
    gld_lds16(Qb_ + (size_t)r0_ * 192 + cc0_, &Qs[buf_][c0_ * 8]); \
    int c1_ = tid + 256, r1_ = c1_ >> 2, cc1_ = (c1_ & 3) << 3; \
    gld_lds16(Qb_ + (size_t)r1_ * 192 + cc1_, &Qs[buf_][c1_ * 8]); \
    const bf16* Kb_ = k + ((size_t)(b * 3 + (h_)) * 2048 + s0) * 192 + (kt_) * 32; \
    gld_lds16(Kb_ + (size_t)(tid >> 2) * 192 + ((tid & 3) << 3), &Ks[buf_][tid * 8]); \
  } while (0)

  SSTAGE(0, 0, 0);
  int step = 0;
  #pragma unroll
  for (int h = 0; h < 3; ++h) {
    #pragma unroll
    for (int kt = 0; kt < 6; ++kt, ++step) {
      __syncthreads();
      const int buf = step & 1;
      int nh = h, nkt = kt + 1;
      if (nkt == 6) { nkt = 0; ++nh; }
      if (nh < 3) SSTAGE(buf ^ 1, nh, nkt);
      const int koff = (lane >> 4) * 8;
      bf16x8 af[4], bfr[2];
      #pragma unroll
      for (int m = 0; m < 4; ++m)
        af[m] = *(const bf16x8*)&Qs[buf][(wm*64 + m*16 + (lane & 15))*32 + koff];
      #pragma unroll
      for (int n = 0; n < 2; ++n)
        bfr[n] = *(const bf16x8*)&Ks[buf][(wn*32 + n*16 + (lane & 15))*32 + koff];
      #pragma unroll
      for (int m = 0; m < 4; ++m)
        #pragma unroll
        for (int n = 0; n < 2; ++n)
          acc[h][m][n] = __builtin_amdgcn_mfma_f32_16x16x32_bf16(af[m], bfr[n], acc[h][m][n], 0, 0, 0);
    }
  }
#undef SSTAGE

  float pw[9];
  #pragma unroll
  for (int i = 0; i < 9; ++i) pw[i] = pre_w[i];
  const float rsq = 0.07216878364870323f;  // 1/sqrt(192)
  #pragma unroll
  for (int m = 0; m < 4; ++m) {
    #pragma unroll
    for (int n = 0; n < 2; ++n) {
      const int col = s0 + wn*32 + n*16 + (lane & 15);
      const int rtop = t0 + wm*64 + m*16 + ((lane >> 4) << 2);
      #pragma unroll
      for (int j = 0; j < 4; ++j) {
        const int row = rtop + j;
        #pragma unroll
        for (int g = 0; g < 3; ++g) {
          const float v = (acc[0][m][n][j]*pw[g] + acc[1][m][n][j]*pw[3+g] + acc[2][m][n][j]*pw[6+g]) * rsq;
          S[(((size_t)zb * 3 + g) * 2048 + row) * 2048 + col] = __float2bfloat16(v);
        }
      }
    }
  }
}

// ---------------- softmax over s + post_w head mix, in-place on S slab ----------------
__global__ __launch_bounds__(256) void softmax_mix_k(
    bf16* __restrict__ S, const float* __restrict__ post_w)
{
  const int t = blockIdx.x, zb = blockIdx.y;
  const int tid = threadIdx.x, lane = tid & 63, wid = tid >> 6;
  float v[3][8];
  #pragma unroll
  for (int g = 0; g < 3; ++g) {
    const u16x8 raw = *(const u16x8*)(S + (((size_t)zb * 3 + g) * 2048 + t) * 2048 + tid * 8);
    #pragma unroll
    for (int j = 0; j < 8; ++j) v[g][j] = __uint_as_float((unsigned)raw[j] << 16);
  }
  __shared__ float red[4][3];
  float mx[3];
  #pragma unroll
  for (int g = 0; g < 3; ++g) {
    float m = v[g][0];
    #pragma unroll
    for (int j = 1; j < 8; ++j) m = fmaxf(m, v[g][j]);
    #pragma unroll
    for (int o = 32; o; o >>= 1) m = fmaxf(m, __shfl_xor(m, o));
    if (lane == 0) red[wid][g] = m;
  }
  __syncthreads();
  #pragma unroll
  for (int g = 0; g < 3; ++g)
    mx[g] = fmaxf(fmaxf(red[0][g], red[1][g]), fmaxf(red[2][g], red[3][g]));
  __syncthreads();
  float e[3][8], inv[3];
  #pragma unroll
  for (int g = 0; g < 3; ++g) {
    float s = 0.f;
    #pragma unroll
    for (int j = 0; j < 8; ++j) { e[g][j] = __expf(v[g][j] - mx[g]); s += e[g][j]; }
    #pragma unroll
    for (int o = 32; o; o >>= 1) s += __shfl_xor(s, o);
    if (lane == 0) red[wid][g] = s;
  }
  __syncthreads();
  #pragma unroll
  for (int g = 0; g < 3; ++g)
    inv[g] = 1.f / (red[0][g] + red[1][g] + red[2][g] + red[3][g]);
  float pw[9];
  #pragma unroll
  for (int i = 0; i < 9; ++i) pw[i] = post_w[i];
  #pragma unroll
  for (int g2 = 0; g2 < 3; ++g2) {
    bf16* orow = S + (((size_t)zb * 3 + g2) * 2048 + t) * 2048 + tid * 8;
    #pragma unroll
    for (int j = 0; j < 8; ++j) {
      float p = e[0][j]*inv[0]*pw[g2] + e[1][j]*inv[1]*pw[3+g2] + e[2][j]*inv[2]*pw[6+g2];
      orow[j] = __float2bfloat16(p);
    }
  }
}

// ---------------- host launcher ----------------
extern "C" void kernel_launch(void* const* d_in, const int* in_sizes, int n_in,
                              void* d_out, int out_size, void* d_ws, size_t ws_size,
                              hipStream_t stream)
{
  (void)in_sizes; (void)n_in; (void)out_size;
  const float* x      = (const float*)d_in[0];
  const float* gamma1 = (const float*)d_in[1];
  const float* beta1  = (const float*)d_in[2];
  const float* gamma2 = (const float*)d_in[3];
  const float* beta2  = (const float*)d_in[4];
  const float* wq     = (const float*)d_in[5];
  const float* wk     = (const float*)d_in[6];
  const float* wv     = (const float*)d_in[7];
  const float* wo     = (const float*)d_in[8];
  const float* pre_w  = (const float*)d_in[9];
  const float* post_w = (const float*)d_in[10];
  const float* w1     = (const float*)d_in[11];
  const float* b1     = (const float*)d_in[12];
  const float* w2     = (const float*)d_in[13];
  const float* b2     = (const float*)d_in[14];
  float* out = (float*)d_out;

  uint8_t* base = (uint8_t*)d_ws;
  size_t off = 0;
  auto alloc = [&](size_t bytes) {
    uint8_t* r = base + off; off += (bytes + 255) & ~(size_t)255; return r;
  };
  bf16* nb    = (bf16*)alloc((size_t)16384 * 192 * 2);    // n1 / n2
  bf16* qb    = (bf16*)alloc((size_t)9437184 * 2);        // q [B,H,T,KD]
  bf16* kb    = (bf16*)alloc((size_t)9437184 * 2);        // k [B,H,T,KD]
  bf16* vTb   = (bf16*)alloc((size_t)9437184 * 2);        // vT [B,H,KD,T]
  bf16* ctxb  = (bf16*)alloc((size_t)16384 * 576 * 2);    // ctx [BT, H*KD]
  bf16* WqkvT = (bf16*)alloc((size_t)331776 * 2);
  bf16* woT   = (bf16*)alloc((size_t)110592 * 2);
  bf16* w1T   = (bf16*)alloc((size_t)147456 * 2);
  bf16* w2T   = (bf16*)alloc((size_t)147456 * 2);
  bf16* hb    = qb;  // overlay: q/k dead by MLP time (25.2MB fits in q+k 37.7MB)

  const size_t sbytes = (size_t)3 * 2048 * 2048 * 2;      // per-batch S slab (bf16)
  int chunk = 1;
  if (off + 8 * sbytes <= ws_size)      chunk = 8;
  else if (off + 4 * sbytes <= ws_size) chunk = 4;
  else if (off + 2 * sbytes <= ws_size) chunk = 2;
  bf16* Sslab = (bf16*)alloc((size_t)chunk * sbytes);

  prep_weights<<<2880, 256, 0, stream>>>(wq, wk, wv, wo, w1, w2, WqkvT, woT, w1T, w2T);
  ln_k<<<4096, 256, 0, stream>>>(x, gamma1, beta1, nb);
  gemm_bt<EPI_QKV><<<dim3(27, 128, 1), 256, 0, stream>>>(nb, WqkvT, 16384, 1728, 192,
      nullptr, nullptr, nullptr, nullptr, qb, kb, vTb, 0);
  for (int b0 = 0; b0 < 8; b0 += chunk) {
    scores_k<<<dim3(32, 16, chunk), 256, 0, stream>>>(qb, kb, pre_w, Sslab, b0);
    softmax_mix_k<<<dim3(2048, chunk), 256, 0, stream>>>(Sslab, post_w);
    gemm_bt<EPI_CTX><<<dim3(3, 16, chunk * 3), 256, 0, stream>>>(Sslab, vTb, 2048, 192, 2048,
        nullptr, ctxb, nullptr, nullptr, nullptr, nullptr, nullptr, b0);
  }
  gemm_bt<EPI_RES><<<dim3(3, 128, 1), 256, 0, stream>>>(ctxb, woT, 16384, 192, 576,
      out, nullptr, nullptr, x, nullptr, nullptr, nullptr, 0);
  ln_k<<<4096, 256, 0, stream>>>(out, gamma2, beta2, nb);
  gemm_bt<EPI_GELU><<<dim3(12, 128, 1), 256, 0, stream>>>(nb, w1T, 16384, 768, 192,
      nullptr, hb, b1, nullptr, nullptr, nullptr, nullptr, 0);
  gemm_bt<EPI_OUT><<<dim3(3, 128, 1), 256, 0, stream>>>(hb, w2T, 16384, 192, 768,
      out, nullptr, b2, nullptr, nullptr, nullptr, nullptr, 0);
}